// Round 16
// baseline (190.963 us; speedup 1.0000x reference)
//
#include <hip/hip_runtime.h>
#include <stdint.h>

// GAT layer: N nodes, E edges, IN=128 -> H*C=128, H=4 heads, C=32.
// Pipeline (6 dispatches):
//   k_wprep : Wt[n][k] = bf16(W[k][n])  (tiny)
//   k_mega  : role-split dispatch, NO inter-role dependency:
//             blocks [0,ngb)   : gemm — h(bf16) = bf16(x)@Wt via mfma_f32_16x16x32_bf16
//                               (Wt in swizzled LDS) + LDS repack -> wide h stores
//                               + alpha from the bf16 LDS tile (dot + 1 shfl)
//             blocks [ngb,+256): per-(bucket,block) dst histogram (bucket = dst>>6);
//                               hist block 0 resets the scan ticket counter
//   k_scan  : chunk-exclusive scan of cnt2; LAST block (device-scope atomic ticket,
//             fenced; stale-L2-safe atomic reads) scans the 1563 chunk sums in-kernel
//   k_fill2 : deterministic edge scatter into ebuf, LDS cursors only
//   k_sort  : per-bucket counting sort ebuf -> node-sorted adj + off
//   k_gather: wave-per-node gather-accumulate; p = exp(lrelu(asrc[s]+adh)) inline,
//             online denominator (softmax without max-shift: logits bounded,
//             shift-invariant), 8-deep unrolled gathers (VGPR 24 -> occupancy 72%;
//             R15 showed deeper unroll trades occupancy for nothing: fetch-bound).

#define NBLK 256    // partition blocks
#define BKT 64      // dst nodes per bucket

typedef __bf16 bf16x8 __attribute__((ext_vector_type(8)));
typedef float f32x4 __attribute__((ext_vector_type(4)));

__device__ __forceinline__ float lrelu(float x) { return x >= 0.f ? x : 0.2f * x; }
__device__ __forceinline__ float blo(unsigned u) { return __uint_as_float(u << 16); }
__device__ __forceinline__ float bhi(unsigned u) { return __uint_as_float(u & 0xffff0000u); }

__global__ __launch_bounds__(256) void k_wprep(const float* __restrict__ W, __bf16* __restrict__ Wt) {
  int idx = blockIdx.x * 256 + threadIdx.x;   // grid = 64 blocks covers 128*128
  int nn = idx & 127, k = idx >> 7;
  Wt[nn * 128 + k] = (__bf16)W[k * 128 + nn];
}

__global__ __launch_bounds__(256) void k_mega(const float* __restrict__ x, const __bf16* __restrict__ Wt,
                                              const float* __restrict__ a_src, const float* __restrict__ a_dst,
                                              __bf16* __restrict__ h, float* __restrict__ asrc,
                                              float* __restrict__ adst,
                                              const int* __restrict__ ei, int* __restrict__ cnt2,
                                              int* __restrict__ done,
                                              int n, int e, int NB, int CE, int ngb) {
  __shared__ __align__(16) char Wl[32768];          // gemm: Wt swizzled | hist: histogram
  __shared__ __align__(16) __bf16 hbuf[4][16 * 64]; // gemm: per-wave half-width out tile
  int t = threadIdx.x;

  if ((int)blockIdx.x >= ngb) {
    // ---- hist role: per-(bucket,block) histogram ----
    int hblk = (int)blockIdx.x - ngb;
    if (hblk == 0 && t == 0) *done = 0;   // reset scan ticket (stream order covers k_scan)
    int* hist = (int*)Wl;
    for (int j = t; j < NB; j += 256) hist[j] = 0;
    __syncthreads();
    int i0 = hblk * CE, i1 = min(e, i0 + CE);
    for (int i = i0 + t; i < i1; i += 256) atomicAdd(&hist[ei[e + i] >> 6], 1);
    __syncthreads();
    for (int j = t; j < NB; j += 256) cnt2[j * NBLK + hblk] = hist[j];
    return;
  }

  // ---- gemm role ----
  {
    const float4* s4 = (const float4*)Wt;
    for (int i = t; i < 2048; i += 256) {
      int f = i << 4;
      int nr = f >> 8, c = f & 255;
      *(float4*)(Wl + ((nr << 8) | (c ^ ((nr & 7) << 4)))) = s4[i];
    }
  }
  __syncthreads();
  int wv = t >> 6, lane = t & 63;
  int arow = lane & 15, ag = lane >> 4, c15 = lane & 15;
  int strip = blockIdx.x * 64 + wv * 16;
  int row = strip + arow;
  float4 fa[8];
  if (row < n) {
    const float4* xr = (const float4*)(x + (size_t)row * 128);
#pragma unroll
    for (int q = 0; q < 4; ++q) {
      fa[2 * q]     = xr[q * 8 + ag * 2];
      fa[2 * q + 1] = xr[q * 8 + ag * 2 + 1];
    }
  } else {
#pragma unroll
    for (int q = 0; q < 8; ++q) fa[q] = make_float4(0.f, 0.f, 0.f, 0.f);
  }
  bf16x8 af[4];
#pragma unroll
  for (int q = 0; q < 4; ++q) {
    af[q][0] = (__bf16)fa[2 * q].x;     af[q][1] = (__bf16)fa[2 * q].y;
    af[q][2] = (__bf16)fa[2 * q].z;     af[q][3] = (__bf16)fa[2 * q].w;
    af[q][4] = (__bf16)fa[2 * q + 1].x; af[q][5] = (__bf16)fa[2 * q + 1].y;
    af[q][6] = (__bf16)fa[2 * q + 1].z; af[q][7] = (__bf16)fa[2 * q + 1].w;
  }
  f32x4 acc[8];
#pragma unroll
  for (int tile = 0; tile < 8; ++tile) acc[tile] = (f32x4){0.f, 0.f, 0.f, 0.f};
#pragma unroll
  for (int q = 0; q < 4; ++q) {
    int gb = (q * 64) + (ag << 4);
#pragma unroll
    for (int tile = 0; tile < 8; ++tile) {
      int nn = tile * 16 + c15;
      bf16x8 bf = *(const bf16x8*)(Wl + ((nn << 8) | (gb ^ ((nn & 7) << 4))));
      acc[tile] = __builtin_amdgcn_mfma_f32_16x16x32_bf16(af[q], bf, acc[tile], 0, 0, 0);
    }
  }
  // per half (64 cols = heads 2*half, 2*half+1): repack -> store h -> alpha from LDS
  int rr = lane >> 2, qq = lane & 3;
  int ro = strip + rr;
  int row16 = lane & 15;
  int hh2 = (lane >> 4) & 1;
  int chunk = lane >> 5;               // 16-ch chunk within the head's 32 ch
#pragma unroll
  for (int half = 0; half < 2; ++half) {
#pragma unroll
    for (int tile = 0; tile < 4; ++tile) {
#pragma unroll
      for (int r = 0; r < 4; ++r)
        hbuf[wv][(ag * 4 + r) * 64 + tile * 16 + c15] = (__bf16)acc[half * 4 + tile][r];
    }
    if (ro < n) {
      const float4* src = (const float4*)&hbuf[wv][rr * 64 + qq * 16];
      float4* dst = (float4*)(h + (size_t)ro * 128 + half * 64 + qq * 16);
      dst[0] = src[0];
      dst[1] = src[1];
    }
    // alpha: lane = (row16, hh2, chunk); dot over 16 channels from the bf16 tile
    int headg = half * 2 + hh2;
    const unsigned* hrow = (const unsigned*)&hbuf[wv][row16 * 64 + hh2 * 32 + chunk * 16];
    const float* asv = a_src + headg * 32 + chunk * 16;
    const float* adv = a_dst + headg * 32 + chunk * 16;
    float ps = 0.f, pd = 0.f;
#pragma unroll
    for (int c = 0; c < 8; ++c) {
      unsigned u = hrow[c];
      float lo = blo(u), hi = bhi(u);
      ps += lo * asv[2 * c] + hi * asv[2 * c + 1];
      pd += lo * adv[2 * c] + hi * adv[2 * c + 1];
    }
    ps += __shfl_xor(ps, 32, 64);
    pd += __shfl_xor(pd, 32, 64);
    if (chunk == 0) {
      int ro2 = strip + row16;
      if (ro2 < n) { asrc[ro2 * 4 + headg] = ps; adst[ro2 * 4 + headg] = pd; }
    }
  }
}

// chunk-exclusive scan of cnt2; last block (atomic ticket) scans chunk sums
__global__ __launch_bounds__(256) void k_scan(int* __restrict__ cnt2, int* __restrict__ bsums,
                                              int* __restrict__ done, int m, int gridA) {
  __shared__ int wsum[4];
  __shared__ int amLast;
  int t = threadIdx.x, i = blockIdx.x * 256 + t;
  int wv = t >> 6, lane = t & 63;
  int v = (i < m) ? cnt2[i] : 0;
  int sc = v;
#pragma unroll
  for (int ofs = 1; ofs < 64; ofs <<= 1) {
    int u = __shfl_up(sc, ofs, 64);
    if (lane >= ofs) sc += u;
  }
  if (lane == 63) wsum[wv] = sc;
  __syncthreads();
  int base = 0;
  for (int w = 0; w < wv; ++w) base += wsum[w];
  if (i < m) cnt2[i] = base + sc - v;
  if (t == 255) {
    bsums[blockIdx.x] = base + sc;
    __threadfence();                          // writer-side fence before ticket
    amLast = (atomicAdd(done, 1) == gridA - 1);
  }
  __syncthreads();
  if (!amLast) return;
  __threadfence();
  // scan bsums[0..gridA) — atomic reads bypass any stale per-XCD L2 copy
  int carry = 0;
  for (int c = 0; c < gridA; c += 256) {
    int ii = c + t;
    int vv = (ii < gridA) ? atomicAdd(&bsums[ii], 0) : 0;
    int s2 = vv;
#pragma unroll
    for (int ofs = 1; ofs < 64; ofs <<= 1) {
      int u = __shfl_up(s2, ofs, 64);
      if (lane >= ofs) s2 += u;
    }
    if (lane == 63) wsum[wv] = s2;
    __syncthreads();
    int b2 = carry;
    for (int w = 0; w < wv; ++w) b2 += wsum[w];
    if (ii < gridA) bsums[ii] = b2 + s2 - vv;
    carry += wsum[0] + wsum[1] + wsum[2] + wsum[3];
    __syncthreads();
  }
}

// ebuf scatter; global base = cnt2 (chunk-exclusive) + bsums (folded here)
__global__ __launch_bounds__(256) void k_fill2(const int* __restrict__ ei, const int* __restrict__ cnt2,
                                               const int* __restrict__ bsums,
                                               unsigned* __restrict__ ebuf, int e, int NB, int CE) {
  __shared__ int cur[2048];
  int t = threadIdx.x, blk = blockIdx.x;
  for (int j = t; j < NB; j += 256) {
    int idx = j * NBLK + blk;
    cur[j] = cnt2[idx] + bsums[idx >> 8];
  }
  __syncthreads();
  int i0 = blk * CE, i1 = min(e, i0 + CE);
  for (int i = i0 + t; i < i1; i += 256) {
    int s = ei[i], d = ei[e + i];
    int pos = atomicAdd(&cur[d >> 6], 1);    // LDS atomic only
    ebuf[pos] = ((unsigned)(d & 63) << 26) | (unsigned)s;
  }
}

// per-bucket counting sort -> node-sorted adj + off
__global__ __launch_bounds__(256) void k_sort(const unsigned* __restrict__ ebuf, const int* __restrict__ cnt2,
                                              const int* __restrict__ bsums,
                                              int* __restrict__ off, int* __restrict__ adj, int n, int NB, int e) {
  __shared__ int lcnt[BKT], lcur[BKT];
  int b = blockIdx.x, t = threadIdx.x;
  int wv = t >> 6, lane = t & 63;
  int i0 = b * NBLK;
  int s0 = cnt2[i0] + bsums[i0 >> 8];
  int s1 = e;
  if (b + 1 < NB) { int i1 = (b + 1) * NBLK; s1 = cnt2[i1] + bsums[i1 >> 8]; }
  int cnt = s1 - s0;
  int d0 = b * BKT;
  if (t < BKT) lcnt[t] = 0;
  __syncthreads();
  for (int j = t; j < cnt; j += 256) atomicAdd(&lcnt[ebuf[s0 + j] >> 26], 1);
  __syncthreads();
  if (wv == 0) {                       // 64-lane scan of bucket-local counts
    int v = lcnt[lane];
    int sc = v;
#pragma unroll
    for (int o = 1; o < 64; o <<= 1) {
      int u = __shfl_up(sc, o, 64);
      if (lane >= o) sc += u;
    }
    lcur[lane] = sc - v;
    if (d0 + lane < n) off[d0 + lane] = s0 + sc - v;
  }
  if (b == 0 && t == 0) off[n] = e;
  __syncthreads();
  for (int j = t; j < cnt; j += 256) {
    unsigned u = ebuf[s0 + j];
    int pos = atomicAdd(&lcur[u >> 26], 1);
    adj[s0 + pos] = (int)(u & 0x03FFFFFFu);
  }
}

// wave-per-node gather-accumulate; p computed inline from L2-resident asrc
__global__ __launch_bounds__(256) void k_gather(const int* __restrict__ adj, const int* __restrict__ off,
                                                const float* __restrict__ asrc, const float* __restrict__ adst,
                                                const unsigned* __restrict__ h32,
                                                const float* __restrict__ bias, float* __restrict__ out, int n) {
  int gid = blockIdx.x * 256 + threadIdx.x;
  int node = gid >> 6, lane = gid & 63;
  if (node >= n) return;
  int head = lane >> 4;
  int o = off[node], oe = off[node + 1];
  float adh = adst[node * 4 + head];
  float ps = __expf(lrelu(asrc[node * 4 + head] + adh));   // self loop
  unsigned su = h32[((unsigned)node << 6) + lane];
  float acc0 = ps * blo(su), acc1 = ps * bhi(su), dtot = ps;
  int j = o;
  for (; j + 8 <= oe; j += 8) {
    int sv[8];
    unsigned hu[8];
    float av[8];
#pragma unroll
    for (int k = 0; k < 8; ++k) sv[k] = adj[j + k];
#pragma unroll
    for (int k = 0; k < 8; ++k) {
      hu[k] = h32[((unsigned)sv[k] << 6) + lane];
      av[k] = asrc[sv[k] * 4 + head];
    }
#pragma unroll
    for (int k = 0; k < 8; ++k) {
      float p = __expf(lrelu(av[k] + adh));
      dtot += p;
      acc0 += p * blo(hu[k]);
      acc1 += p * bhi(hu[k]);
    }
  }
  for (; j + 2 <= oe; j += 2) {
    int sA = adj[j], sB = adj[j + 1];
    unsigned uA = h32[((unsigned)sA << 6) + lane];
    unsigned uB = h32[((unsigned)sB << 6) + lane];
    float pA = __expf(lrelu(asrc[sA * 4 + head] + adh));
    float pB = __expf(lrelu(asrc[sB * 4 + head] + adh));
    dtot += pA + pB;
    acc0 += pA * blo(uA) + pB * blo(uB);
    acc1 += pA * bhi(uA) + pB * bhi(uB);
  }
  if (j < oe) {
    int s = adj[j];
    unsigned u = h32[((unsigned)s << 6) + lane];
    float p = __expf(lrelu(asrc[s * 4 + head] + adh));
    dtot += p;
    acc0 += p * blo(u);
    acc1 += p * bhi(u);
  }
  float inv = 1.f / dtot;
  float2 bb = ((const float2*)bias)[lane];
  ((float2*)(out + (size_t)node * 128))[lane] = make_float2(acc0 * inv + bb.x, acc1 * inv + bb.y);
}

extern "C" void kernel_launch(void* const* d_in, const int* in_sizes, int n_in,
                              void* d_out, int out_size, void* d_ws, size_t ws_size,
                              hipStream_t stream) {
  const float* x     = (const float*)d_in[0];
  const int*   ei    = (const int*)d_in[1];
  const float* W     = (const float*)d_in[2];
  const float* a_src = (const float*)d_in[3];
  const float* a_dst = (const float*)d_in[4];
  const float* bias  = (const float*)d_in[5];
  float* out = (float*)d_out;

  int n = in_sizes[0] / 128;   // IN = 128
  int e = in_sizes[1] / 2;
  int NB = (n + BKT - 1) / BKT;   // dst buckets of 64 nodes
  int ngb = (n + 63) / 64;        // gemm role blocks
  int m = NB * NBLK;
  int gridA = (m + 255) / 256;
  int CE = (e + NBLK - 1) / NBLK;

  char* ws = (char*)d_ws;
  size_t ofs = 0;
  auto alloc = [&](size_t bytes) { void* p = ws + ofs; ofs = (ofs + bytes + 15) & ~(size_t)15; return p; };
  __bf16* h      = (__bf16*)alloc((size_t)n * 128 * sizeof(__bf16));    // 25.6 MB
  unsigned* h32  = (unsigned*)h;
  float* asrc    = (float*)alloc((size_t)n * 4 * sizeof(float));
  float* adst    = (float*)alloc((size_t)n * 4 * sizeof(float));
  int* off       = (int*)alloc((size_t)(n + 1) * sizeof(int));
  int* cnt2      = (int*)alloc((size_t)m * sizeof(int));                // 1.6 MB
  int* bsums     = (int*)alloc((size_t)gridA * sizeof(int));
  int* done      = (int*)alloc(sizeof(int));
  unsigned* ebuf = (unsigned*)alloc((size_t)e * sizeof(unsigned));      // 6.4 MB
  int* adj       = (int*)alloc((size_t)e * sizeof(int));                // 6.4 MB
  __bf16* Wt     = (__bf16*)alloc((size_t)128 * 128 * sizeof(__bf16));  // 32 KB

  hipLaunchKernelGGL(k_wprep, dim3(64), dim3(256), 0, stream, W, Wt);
  hipLaunchKernelGGL(k_mega, dim3(ngb + NBLK), dim3(256), 0, stream,
                     x, Wt, a_src, a_dst, h, asrc, adst, ei, cnt2, done, n, e, NB, CE, ngb);
  hipLaunchKernelGGL(k_scan, dim3(gridA), dim3(256), 0, stream, cnt2, bsums, done, m, gridA);
  hipLaunchKernelGGL(k_fill2, dim3(NBLK), dim3(256), 0, stream, ei, cnt2, bsums, ebuf, e, NB, CE);
  hipLaunchKernelGGL(k_sort, dim3(NB), dim3(256), 0, stream, ebuf, cnt2, bsums, off, adj, n, NB, e);
  hipLaunchKernelGGL(k_gather, dim3((n * 64 + 255) / 256), dim3(256), 0, stream,
                     adj, off, asrc, adst, h32, bias, out, n);
}

// Round 17
// 160.358 us; speedup vs baseline: 1.1909x; 1.1909x over previous
//
#include <hip/hip_runtime.h>
#include <stdint.h>

// GAT layer: N nodes, E edges, IN=128 -> H*C=128, H=4 heads, C=32.
// Pipeline (7 dispatches) — best-measured configuration of each component:
//   k_wprep : Wt[n][k] = bf16(W[k][n])  (tiny)
//   k_mega  : role-split dispatch, NO inter-role dependency:
//             blocks [0,ngb)   : gemm — h(bf16) = bf16(x)@Wt via mfma_f32_16x16x32_bf16
//                               (Wt in swizzled LDS) + LDS repack -> wide h stores
//                               + alpha from the bf16 LDS tile (dot + 1 shfl)
//             blocks [ngb,+128): per-(bucket,block) dst histogram (bucket = dst>>6)
//   k_scanA/B : hierarchical exclusive scan of cnt2 (bsums folded at read time)
//   k_fill2 : deterministic edge scatter into ebuf, LDS cursors only (NBLK=128:
//             ~8 edges per bucket region -> 32B-per-64B-line writes; R16 showed 256
//             blocks doubles write amplification)
//   k_sort  : per-bucket counting sort ebuf -> node-sorted adj + off
//   k_gather: wave-per-node gather-accumulate; p = exp(lrelu(asrc[s]+adh)) inline,
//             online denominator (softmax without max-shift: logits bounded,
//             shift-invariant), 8-deep unrolled gathers (VGPR 24 -> occupancy 72%;
//             R15 proved deeper unroll trades occupancy for nothing: fetch-bound).

#define NBLK 128    // partition blocks
#define BKT 64      // dst nodes per bucket

typedef __bf16 bf16x8 __attribute__((ext_vector_type(8)));
typedef float f32x4 __attribute__((ext_vector_type(4)));

__device__ __forceinline__ float lrelu(float x) { return x >= 0.f ? x : 0.2f * x; }
__device__ __forceinline__ float blo(unsigned u) { return __uint_as_float(u << 16); }
__device__ __forceinline__ float bhi(unsigned u) { return __uint_as_float(u & 0xffff0000u); }

__global__ __launch_bounds__(256) void k_wprep(const float* __restrict__ W, __bf16* __restrict__ Wt) {
  int idx = blockIdx.x * 256 + threadIdx.x;   // grid = 64 blocks covers 128*128
  int nn = idx & 127, k = idx >> 7;
  Wt[nn * 128 + k] = (__bf16)W[k * 128 + nn];
}

__global__ __launch_bounds__(256) void k_mega(const float* __restrict__ x, const __bf16* __restrict__ Wt,
                                              const float* __restrict__ a_src, const float* __restrict__ a_dst,
                                              __bf16* __restrict__ h, float* __restrict__ asrc,
                                              float* __restrict__ adst,
                                              const int* __restrict__ ei, int* __restrict__ cnt2,
                                              int n, int e, int NB, int CE, int ngb) {
  __shared__ __align__(16) char Wl[32768];          // gemm: Wt swizzled | hist: histogram
  __shared__ __align__(16) __bf16 hbuf[4][16 * 64]; // gemm: per-wave half-width out tile
  int t = threadIdx.x;

  if ((int)blockIdx.x >= ngb) {
    // ---- hist role: per-(bucket,block) histogram ----
    int hblk = (int)blockIdx.x - ngb;
    int* hist = (int*)Wl;
    for (int j = t; j < NB; j += 256) hist[j] = 0;
    __syncthreads();
    int i0 = hblk * CE, i1 = min(e, i0 + CE);
    for (int i = i0 + t; i < i1; i += 256) atomicAdd(&hist[ei[e + i] >> 6], 1);
    __syncthreads();
    for (int j = t; j < NB; j += 256) cnt2[j * NBLK + hblk] = hist[j];
    return;
  }

  // ---- gemm role ----
  {
    const float4* s4 = (const float4*)Wt;
    for (int i = t; i < 2048; i += 256) {
      int f = i << 4;
      int nr = f >> 8, c = f & 255;
      *(float4*)(Wl + ((nr << 8) | (c ^ ((nr & 7) << 4)))) = s4[i];
    }
  }
  __syncthreads();
  int wv = t >> 6, lane = t & 63;
  int arow = lane & 15, ag = lane >> 4, c15 = lane & 15;
  int strip = blockIdx.x * 64 + wv * 16;
  int row = strip + arow;
  float4 fa[8];
  if (row < n) {
    const float4* xr = (const float4*)(x + (size_t)row * 128);
#pragma unroll
    for (int q = 0; q < 4; ++q) {
      fa[2 * q]     = xr[q * 8 + ag * 2];
      fa[2 * q + 1] = xr[q * 8 + ag * 2 + 1];
    }
  } else {
#pragma unroll
    for (int q = 0; q < 8; ++q) fa[q] = make_float4(0.f, 0.f, 0.f, 0.f);
  }
  bf16x8 af[4];
#pragma unroll
  for (int q = 0; q < 4; ++q) {
    af[q][0] = (__bf16)fa[2 * q].x;     af[q][1] = (__bf16)fa[2 * q].y;
    af[q][2] = (__bf16)fa[2 * q].z;     af[q][3] = (__bf16)fa[2 * q].w;
    af[q][4] = (__bf16)fa[2 * q + 1].x; af[q][5] = (__bf16)fa[2 * q + 1].y;
    af[q][6] = (__bf16)fa[2 * q + 1].z; af[q][7] = (__bf16)fa[2 * q + 1].w;
  }
  f32x4 acc[8];
#pragma unroll
  for (int tile = 0; tile < 8; ++tile) acc[tile] = (f32x4){0.f, 0.f, 0.f, 0.f};
#pragma unroll
  for (int q = 0; q < 4; ++q) {
    int gb = (q * 64) + (ag << 4);
#pragma unroll
    for (int tile = 0; tile < 8; ++tile) {
      int nn = tile * 16 + c15;
      bf16x8 bf = *(const bf16x8*)(Wl + ((nn << 8) | (gb ^ ((nn & 7) << 4))));
      acc[tile] = __builtin_amdgcn_mfma_f32_16x16x32_bf16(af[q], bf, acc[tile], 0, 0, 0);
    }
  }
  // per half (64 cols = heads 2*half, 2*half+1): repack -> store h -> alpha from LDS
  int rr = lane >> 2, qq = lane & 3;
  int ro = strip + rr;
  int row16 = lane & 15;
  int hh2 = (lane >> 4) & 1;
  int chunk = lane >> 5;               // 16-ch chunk within the head's 32 ch
#pragma unroll
  for (int half = 0; half < 2; ++half) {
#pragma unroll
    for (int tile = 0; tile < 4; ++tile) {
#pragma unroll
      for (int r = 0; r < 4; ++r)
        hbuf[wv][(ag * 4 + r) * 64 + tile * 16 + c15] = (__bf16)acc[half * 4 + tile][r];
    }
    if (ro < n) {
      const float4* src = (const float4*)&hbuf[wv][rr * 64 + qq * 16];
      float4* dst = (float4*)(h + (size_t)ro * 128 + half * 64 + qq * 16);
      dst[0] = src[0];
      dst[1] = src[1];
    }
    // alpha: lane = (row16, hh2, chunk); dot over 16 channels from the bf16 tile
    int headg = half * 2 + hh2;
    const unsigned* hrow = (const unsigned*)&hbuf[wv][row16 * 64 + hh2 * 32 + chunk * 16];
    const float* asv = a_src + headg * 32 + chunk * 16;
    const float* adv = a_dst + headg * 32 + chunk * 16;
    float ps = 0.f, pd = 0.f;
#pragma unroll
    for (int c = 0; c < 8; ++c) {
      unsigned u = hrow[c];
      float lo = blo(u), hi = bhi(u);
      ps += lo * asv[2 * c] + hi * asv[2 * c + 1];
      pd += lo * adv[2 * c] + hi * adv[2 * c + 1];
    }
    ps += __shfl_xor(ps, 32, 64);
    pd += __shfl_xor(pd, 32, 64);
    if (chunk == 0) {
      int ro2 = strip + row16;
      if (ro2 < n) { asrc[ro2 * 4 + headg] = ps; adst[ro2 * 4 + headg] = pd; }
    }
  }
}

// --- scans over cnt2 (m = NB*NBLK) ---

__global__ __launch_bounds__(256) void k_scanA(int* __restrict__ cnt2, int* __restrict__ bsums, int m) {
  __shared__ int wsum[4];
  int t = threadIdx.x, i = blockIdx.x * 256 + t;
  int wv = t >> 6, lane = t & 63;
  int v = (i < m) ? cnt2[i] : 0;
  int sc = v;
#pragma unroll
  for (int ofs = 1; ofs < 64; ofs <<= 1) {
    int u = __shfl_up(sc, ofs, 64);
    if (lane >= ofs) sc += u;
  }
  if (lane == 63) wsum[wv] = sc;
  __syncthreads();
  int base = 0;
  for (int w = 0; w < wv; ++w) base += wsum[w];
  if (i < m) cnt2[i] = base + sc - v;
  if (t == 255) bsums[blockIdx.x] = base + sc;
}

__global__ __launch_bounds__(256) void k_scanB(int* __restrict__ bsums, int nbs) {
  __shared__ int wsum[4];
  int t = threadIdx.x, wv = t >> 6, lane = t & 63;
  int carry = 0;
  for (int c = 0; c < nbs; c += 256) {
    int i = c + t;
    int v = (i < nbs) ? bsums[i] : 0;
    int sc = v;
#pragma unroll
    for (int ofs = 1; ofs < 64; ofs <<= 1) {
      int u = __shfl_up(sc, ofs, 64);
      if (lane >= ofs) sc += u;
    }
    if (lane == 63) wsum[wv] = sc;
    __syncthreads();
    int base = carry;
    for (int w = 0; w < wv; ++w) base += wsum[w];
    if (i < nbs) bsums[i] = base + sc - v;
    carry += wsum[0] + wsum[1] + wsum[2] + wsum[3];
    __syncthreads();
  }
}

// ebuf scatter; global base = cnt2 (chunk-exclusive) + bsums (folded here)
__global__ __launch_bounds__(256) void k_fill2(const int* __restrict__ ei, const int* __restrict__ cnt2,
                                               const int* __restrict__ bsums,
                                               unsigned* __restrict__ ebuf, int e, int NB, int CE) {
  __shared__ int cur[2048];
  int t = threadIdx.x, blk = blockIdx.x;
  for (int j = t; j < NB; j += 256) {
    int idx = j * NBLK + blk;
    cur[j] = cnt2[idx] + bsums[idx >> 8];
  }
  __syncthreads();
  int i0 = blk * CE, i1 = min(e, i0 + CE);
  for (int i = i0 + t; i < i1; i += 256) {
    int s = ei[i], d = ei[e + i];
    int pos = atomicAdd(&cur[d >> 6], 1);    // LDS atomic only
    ebuf[pos] = ((unsigned)(d & 63) << 26) | (unsigned)s;
  }
}

// per-bucket counting sort -> node-sorted adj + off
__global__ __launch_bounds__(256) void k_sort(const unsigned* __restrict__ ebuf, const int* __restrict__ cnt2,
                                              const int* __restrict__ bsums,
                                              int* __restrict__ off, int* __restrict__ adj, int n, int NB, int e) {
  __shared__ int lcnt[BKT], lcur[BKT];
  int b = blockIdx.x, t = threadIdx.x;
  int wv = t >> 6, lane = t & 63;
  int i0 = b * NBLK;
  int s0 = cnt2[i0] + bsums[i0 >> 8];
  int s1 = e;
  if (b + 1 < NB) { int i1 = (b + 1) * NBLK; s1 = cnt2[i1] + bsums[i1 >> 8]; }
  int cnt = s1 - s0;
  int d0 = b * BKT;
  if (t < BKT) lcnt[t] = 0;
  __syncthreads();
  for (int j = t; j < cnt; j += 256) atomicAdd(&lcnt[ebuf[s0 + j] >> 26], 1);
  __syncthreads();
  if (wv == 0) {                       // 64-lane scan of bucket-local counts
    int v = lcnt[lane];
    int sc = v;
#pragma unroll
    for (int o = 1; o < 64; o <<= 1) {
      int u = __shfl_up(sc, o, 64);
      if (lane >= o) sc += u;
    }
    lcur[lane] = sc - v;
    if (d0 + lane < n) off[d0 + lane] = s0 + sc - v;
  }
  if (b == 0 && t == 0) off[n] = e;
  __syncthreads();
  for (int j = t; j < cnt; j += 256) {
    unsigned u = ebuf[s0 + j];
    int pos = atomicAdd(&lcur[u >> 26], 1);
    adj[s0 + pos] = (int)(u & 0x03FFFFFFu);
  }
}

// wave-per-node gather-accumulate; p computed inline from L2-resident asrc
__global__ __launch_bounds__(256) void k_gather(const int* __restrict__ adj, const int* __restrict__ off,
                                                const float* __restrict__ asrc, const float* __restrict__ adst,
                                                const unsigned* __restrict__ h32,
                                                const float* __restrict__ bias, float* __restrict__ out, int n) {
  int gid = blockIdx.x * 256 + threadIdx.x;
  int node = gid >> 6, lane = gid & 63;
  if (node >= n) return;
  int head = lane >> 4;
  int o = off[node], oe = off[node + 1];
  float adh = adst[node * 4 + head];
  float ps = __expf(lrelu(asrc[node * 4 + head] + adh));   // self loop
  unsigned su = h32[((unsigned)node << 6) + lane];
  float acc0 = ps * blo(su), acc1 = ps * bhi(su), dtot = ps;
  int j = o;
  for (; j + 8 <= oe; j += 8) {
    int sv[8];
    unsigned hu[8];
    float av[8];
#pragma unroll
    for (int k = 0; k < 8; ++k) sv[k] = adj[j + k];
#pragma unroll
    for (int k = 0; k < 8; ++k) {
      hu[k] = h32[((unsigned)sv[k] << 6) + lane];
      av[k] = asrc[sv[k] * 4 + head];
    }
#pragma unroll
    for (int k = 0; k < 8; ++k) {
      float p = __expf(lrelu(av[k] + adh));
      dtot += p;
      acc0 += p * blo(hu[k]);
      acc1 += p * bhi(hu[k]);
    }
  }
  for (; j + 2 <= oe; j += 2) {
    int sA = adj[j], sB = adj[j + 1];
    unsigned uA = h32[((unsigned)sA << 6) + lane];
    unsigned uB = h32[((unsigned)sB << 6) + lane];
    float pA = __expf(lrelu(asrc[sA * 4 + head] + adh));
    float pB = __expf(lrelu(asrc[sB * 4 + head] + adh));
    dtot += pA + pB;
    acc0 += pA * blo(uA) + pB * blo(uB);
    acc1 += pA * bhi(uA) + pB * bhi(uB);
  }
  if (j < oe) {
    int s = adj[j];
    unsigned u = h32[((unsigned)s << 6) + lane];
    float p = __expf(lrelu(asrc[s * 4 + head] + adh));
    dtot += p;
    acc0 += p * blo(u);
    acc1 += p * bhi(u);
  }
  float inv = 1.f / dtot;
  float2 bb = ((const float2*)bias)[lane];
  ((float2*)(out + (size_t)node * 128))[lane] = make_float2(acc0 * inv + bb.x, acc1 * inv + bb.y);
}

extern "C" void kernel_launch(void* const* d_in, const int* in_sizes, int n_in,
                              void* d_out, int out_size, void* d_ws, size_t ws_size,
                              hipStream_t stream) {
  const float* x     = (const float*)d_in[0];
  const int*   ei    = (const int*)d_in[1];
  const float* W     = (const float*)d_in[2];
  const float* a_src = (const float*)d_in[3];
  const float* a_dst = (const float*)d_in[4];
  const float* bias  = (const float*)d_in[5];
  float* out = (float*)d_out;

  int n = in_sizes[0] / 128;   // IN = 128
  int e = in_sizes[1] / 2;
  int NB = (n + BKT - 1) / BKT;   // dst buckets of 64 nodes
  int ngb = (n + 63) / 64;        // gemm role blocks
  int m = NB * NBLK;
  int gridA = (m + 255) / 256;
  int CE = (e + NBLK - 1) / NBLK;

  char* ws = (char*)d_ws;
  size_t ofs = 0;
  auto alloc = [&](size_t bytes) { void* p = ws + ofs; ofs = (ofs + bytes + 15) & ~(size_t)15; return p; };
  __bf16* h      = (__bf16*)alloc((size_t)n * 128 * sizeof(__bf16));    // 25.6 MB
  unsigned* h32  = (unsigned*)h;
  float* asrc    = (float*)alloc((size_t)n * 4 * sizeof(float));
  float* adst    = (float*)alloc((size_t)n * 4 * sizeof(float));
  int* off       = (int*)alloc((size_t)(n + 1) * sizeof(int));
  int* cnt2      = (int*)alloc((size_t)m * sizeof(int));                // 0.8 MB
  int* bsums     = (int*)alloc((size_t)gridA * sizeof(int));
  unsigned* ebuf = (unsigned*)alloc((size_t)e * sizeof(unsigned));      // 6.4 MB
  int* adj       = (int*)alloc((size_t)e * sizeof(int));                // 6.4 MB
  __bf16* Wt     = (__bf16*)alloc((size_t)128 * 128 * sizeof(__bf16));  // 32 KB

  hipLaunchKernelGGL(k_wprep, dim3(64), dim3(256), 0, stream, W, Wt);
  hipLaunchKernelGGL(k_mega, dim3(ngb + NBLK), dim3(256), 0, stream,
                     x, Wt, a_src, a_dst, h, asrc, adst, ei, cnt2, n, e, NB, CE, ngb);
  hipLaunchKernelGGL(k_scanA, dim3(gridA), dim3(256), 0, stream, cnt2, bsums, m);
  hipLaunchKernelGGL(k_scanB, dim3(1), dim3(256), 0, stream, bsums, gridA);
  hipLaunchKernelGGL(k_fill2, dim3(NBLK), dim3(256), 0, stream, ei, cnt2, bsums, ebuf, e, NB, CE);
  hipLaunchKernelGGL(k_sort, dim3(NB), dim3(256), 0, stream, ebuf, cnt2, bsums, off, adj, n, NB, e);
  hipLaunchKernelGGL(k_gather, dim3((n * 64 + 255) / 256), dim3(256), 0, stream,
                     adj, off, asrc, adst, h32, bias, out, n);
}